// Round 1
// 749.707 us; speedup vs baseline: 1.1666x; 1.1666x over previous
//
#include <hip/hip_runtime.h>
#include <stdint.h>

// y[m,o] = sum_d x[m,d] * (wq[o,d]*scale) + bias[o]
// M = B*S = 16384, N = D_OUT = 4096, K = D_IN = 4096. fp32 out.
// Path: per-row i8 quant of x (only error source; wq is EXACT in i8),
// i8 MFMA, exact i32 accumulate, fp32 dequant epilogue.
//
// GEMM: 256x256 tile, 8 waves (2Mx4N), K-tile = 128 B, 4-phase pipelined
// schedule per K-tile (8-phase template folded), counted vmcnt (never 0 in
// steady state), LDS XOR-swizzle col ^= ((row&7)<<4) via pre-swizzled
// global_load_lds source + swizzled ds_read, setprio around MFMA clusters,
// XCD-aware block swizzle.
constexpr int M = 16384;
constexpr int N = 4096;
constexpr int K = 4096;
constexpr int BM = 256, BN = 256, BKB = 128;  // BKB = K-bytes per tile
constexpr int NT = K / BKB;                   // 32 K-tiles

typedef __attribute__((ext_vector_type(4))) int i32x4;

// x: fp32 -> i8 with per-row scale. One block per row (K=4096, 256 thr x 16).
__global__ __launch_bounds__(256) void quant_x_kernel(
    const float* __restrict__ x, signed char* __restrict__ o,
    float* __restrict__ row_step) {
    const int row = blockIdx.x;
    const int t = threadIdx.x;
    const float* xr = x + (size_t)row * K;
    float4 v[4];
#pragma unroll
    for (int i = 0; i < 4; i++) v[i] = ((const float4*)xr)[t + 256 * i];

    float amax = 0.f;
#pragma unroll
    for (int i = 0; i < 4; i++)
        amax = fmaxf(amax,
               fmaxf(fmaxf(fabsf(v[i].x), fabsf(v[i].y)),
                     fmaxf(fabsf(v[i].z), fabsf(v[i].w))));
#pragma unroll
    for (int off = 32; off > 0; off >>= 1)
        amax = fmaxf(amax, __shfl_xor(amax, off, 64));
    __shared__ float wmax[4];
    if ((t & 63) == 0) wmax[t >> 6] = amax;
    __syncthreads();
    amax = fmaxf(fmaxf(wmax[0], wmax[1]), fmaxf(wmax[2], wmax[3]));

    const float inv = (amax > 0.f) ? 127.0f / amax : 0.f;
    if (t == 0) row_step[row] = (amax > 0.f) ? amax / 127.0f : 0.f;

    signed char* orow = o + (size_t)row * K;
#pragma unroll
    for (int i = 0; i < 4; i++) {
        char4 r;
        r.x = (signed char)__float2int_rn(v[i].x * inv);
        r.y = (signed char)__float2int_rn(v[i].y * inv);
        r.z = (signed char)__float2int_rn(v[i].z * inv);
        r.w = (signed char)__float2int_rn(v[i].w * inv);
        ((char4*)orow)[t + 256 * i] = r;
    }
}

// wq: int32 [0,127] -> i8 (EXACT)
__global__ void quant_w_kernel(const int* __restrict__ q,
                               signed char* __restrict__ o) {
    const int i = blockIdx.x * blockDim.x + threadIdx.x;
    int4 v = ((const int4*)q)[i];
    char4 r;
    r.x = (signed char)v.x; r.y = (signed char)v.y;
    r.z = (signed char)v.z; r.w = (signed char)v.w;
    ((char4*)o)[i] = r;
}

__global__ __launch_bounds__(512, 2) void gemm_i8_kernel(
    const signed char* __restrict__ A,
    const signed char* __restrict__ B,
    const float* __restrict__ row_step,
    const float* __restrict__ scale,
    const float* __restrict__ bias,
    float* __restrict__ C) {
    // [buf][256 rows][128 B], 64 KB each -> 128 KB total (1 block/CU)
    __shared__ __align__(16) signed char As[2 * BM * BKB];
    __shared__ __align__(16) signed char Bs[2 * BN * BKB];

    const int t    = threadIdx.x;
    const int lane = t & 63;
    const int wave = t >> 6;
    const int wr   = wave >> 2;  // 0..1 (M)
    const int wc   = wave & 3;   // 0..3 (N)
    const int r16  = lane & 15;
    const int quad = lane >> 4;

    // T1: XCD-aware swizzle (1024 WGs, divisible by 8), bm-fast so each
    // XCD chunk shares 2 B-panels (2 MB, L2-resident).
    constexpr int NWG = (M / BM) * (N / BN);  // 1024
    constexpr int CPX = NWG / 8;
    const int bid = (blockIdx.x & 7) * CPX + (blockIdx.x >> 3);
    const int bm = bid & (M / BM - 1);
    const int bn = bid >> 6;
    const int mBase = bm * BM;
    const int nBase = bn * BN;

    // Staging: thread t covers row (t>>3) of an 8 KB chunk, col chunk (t&7).
    // Source col pre-swizzled (involution col ^= ((row&7)<<4)) so the
    // LINEAR global_load_lds dest ends up holding the swizzled layout.
    const int sr   = t >> 3;                       // 0..63
    const int scol = ((t & 7) ^ (sr & 7)) << 4;    // pre-swizzled byte col

    typedef __attribute__((address_space(3))) signed char* lds_p;
    typedef const __attribute__((address_space(1))) signed char* g_p;

    const g_p AgS = (g_p)(A + (size_t)(mBase + sr) * K + scol);
    const g_p BgS = (g_p)(B + (size_t)(nBase + sr) * K + scol);

// stage half h (0/1: rows h*128..h*128+127) of K-tile kt into buffer at
// byte offset bofs. 2 x global_load_lds (8 KB each, width=16).
#define STAGE_A(bofs, h, kt) do {                                            \
    __builtin_amdgcn_global_load_lds(                                        \
        AgS + (size_t)((h) * 128) * K + (size_t)(kt) * BKB,                  \
        (lds_p)(As + (bofs) + ((h) << 14) + t * 16), 16, 0, 0);              \
    __builtin_amdgcn_global_load_lds(                                        \
        AgS + (size_t)((h) * 128 + 64) * K + (size_t)(kt) * BKB,             \
        (lds_p)(As + (bofs) + ((h) << 14) + 8192 + t * 16), 16, 0, 0);       \
  } while (0)
#define STAGE_B(bofs, h, kt) do {                                            \
    __builtin_amdgcn_global_load_lds(                                        \
        BgS + (size_t)((h) * 128) * K + (size_t)(kt) * BKB,                  \
        (lds_p)(Bs + (bofs) + ((h) << 14) + t * 16), 16, 0, 0);              \
    __builtin_amdgcn_global_load_lds(                                        \
        BgS + (size_t)((h) * 128 + 64) * K + (size_t)(kt) * BKB,             \
        (lds_p)(Bs + (bofs) + ((h) << 14) + 8192 + t * 16), 16, 0, 0);       \
  } while (0)

    // Fragment read offsets (swizzled). row&7 == r16&7 for all frags.
    int aoff[8], boff[4], csw[2];
#pragma unroll
    for (int m = 0; m < 8; ++m) aoff[m] = (wr * 128 + m * 16 + r16) * BKB;
#pragma unroll
    for (int n = 0; n < 4; ++n) boff[n] = (wc * 64 + n * 16 + r16) * BKB;
    csw[0] = ((0 + quad) ^ (r16 & 7)) << 4;  // ks=0 slice
    csw[1] = ((4 + quad) ^ (r16 & 7)) << 4;  // ks=1 slice

    i32x4 acc[8][4];
    const i32x4 zero = {0, 0, 0, 0};
#pragma unroll
    for (int m = 0; m < 8; ++m)
#pragma unroll
        for (int n = 0; n < 4; ++n) acc[m][n] = zero;

    // Prologue: issue [t0 Bh0, t0 Bh1, t0 Ah0, t0 Ah1, t1 Bh0, t1 Bh1]
    // (12 loads), wait vmcnt(4) -> tile 0 fully resident, t1 B in flight.
    STAGE_B(0, 0, 0);
    STAGE_B(0, 1, 0);
    STAGE_A(0, 0, 0);
    STAGE_A(0, 1, 0);
    STAGE_B(1 << 15, 0, 1);
    STAGE_B(1 << 15, 1, 1);
    asm volatile("s_waitcnt vmcnt(4)" ::: "memory");
    __builtin_amdgcn_s_barrier();

    i32x4 bv[4][2];

    // Steady-state iter kt (buf bO): p0 reads all B + A m0-1, stages
    // A-h0(kt+1)->bX; p1: A m2-3, stage A-h1(kt+1); p2: A m4-5, stage
    // B-h0(kt+2)->bO (B region of bO consumed in p0); p3: A m6-7, stage
    // B-h1(kt+2), vmcnt(4) (leaves kt+2's B halves in flight).
    for (int kt = 0; kt < NT; ++kt) {
        const int bO = (kt & 1) << 15;
        const int bX = bO ^ (1 << 15);
#pragma unroll
        for (int p = 0; p < 4; ++p) {
            const i32x4 a00 = *(const i32x4*)(As + bO + aoff[2 * p] + csw[0]);
            const i32x4 a01 = *(const i32x4*)(As + bO + aoff[2 * p] + csw[1]);
            const i32x4 a10 = *(const i32x4*)(As + bO + aoff[2 * p + 1] + csw[0]);
            const i32x4 a11 = *(const i32x4*)(As + bO + aoff[2 * p + 1] + csw[1]);
            if (p == 0) {
#pragma unroll
                for (int n = 0; n < 4; ++n) {
                    bv[n][0] = *(const i32x4*)(Bs + bO + boff[n] + csw[0]);
                    bv[n][1] = *(const i32x4*)(Bs + bO + boff[n] + csw[1]);
                }
            }
            if (p == 0 && kt + 1 < NT) STAGE_A(bX, 0, kt + 1);
            if (p == 1 && kt + 1 < NT) STAGE_A(bX, 1, kt + 1);
            if (p == 2 && kt + 2 < NT) STAGE_B(bO, 0, kt + 2);
            if (p == 3) {
                if (kt + 2 < NT) STAGE_B(bO, 1, kt + 2);
                if (kt < NT - 2) {
                    asm volatile("s_waitcnt vmcnt(4)" ::: "memory");
                } else if (kt == NT - 2) {
                    asm volatile("s_waitcnt vmcnt(0)" ::: "memory");
                }
            }
            __builtin_amdgcn_s_barrier();
            __builtin_amdgcn_s_setprio(1);
#pragma unroll
            for (int ks = 0; ks < 2; ++ks) {
                const i32x4 x0 = ks ? a01 : a00;
                const i32x4 x1 = ks ? a11 : a10;
#pragma unroll
                for (int n = 0; n < 4; ++n) {
                    acc[2 * p][n] = __builtin_amdgcn_mfma_i32_16x16x64_i8(
                        x0, bv[n][ks], acc[2 * p][n], 0, 0, 0);
                    acc[2 * p + 1][n] = __builtin_amdgcn_mfma_i32_16x16x64_i8(
                        x1, bv[n][ks], acc[2 * p + 1][n], 0, 0, 0);
                }
            }
            __builtin_amdgcn_s_setprio(0);
            __builtin_amdgcn_s_barrier();
        }
    }

    // Epilogue: y = acc * (row_step[row]*scale) + bias[col]
    // C/D layout (shape-determined): col = lane&15, row = quad*4 + reg
    const float s0 = scale[0];
    float bvals[4];
#pragma unroll
    for (int n = 0; n < 4; ++n)
        bvals[n] = bias[nBase + wc * 64 + n * 16 + r16];
    float rsv[8][4];
#pragma unroll
    for (int m = 0; m < 8; ++m)
#pragma unroll
        for (int r = 0; r < 4; ++r)
            rsv[m][r] = row_step[mBase + wr * 128 + m * 16 + quad * 4 + r] * s0;

#pragma unroll
    for (int m = 0; m < 8; ++m) {
#pragma unroll
        for (int n = 0; n < 4; ++n) {
            const int col = nBase + wc * 64 + n * 16 + r16;
#pragma unroll
            for (int r = 0; r < 4; ++r) {
                const int row = mBase + wr * 128 + m * 16 + quad * 4 + r;
                C[(size_t)row * N + col] =
                    (float)acc[m][n][r] * rsv[m][r] + bvals[n];
            }
        }
    }
#undef STAGE_A
#undef STAGE_B
}

extern "C" void kernel_launch(void* const* d_in, const int* in_sizes, int n_in,
                              void* d_out, int out_size, void* d_ws, size_t ws_size,
                              hipStream_t stream) {
    const float* x     = (const float*)d_in[0];
    const int*   wq    = (const int*)d_in[1];
    const float* scale = (const float*)d_in[2];
    const float* bias  = (const float*)d_in[3];
    float*       out   = (float*)d_out;

    // ws layout: row_step [M f32] | x_i8 [M*K] | w_i8 [N*K]  (~80 MB)
    float*       rs = (float*)d_ws;
    signed char* xb = (signed char*)(rs + M);
    signed char* wb = xb + (size_t)M * K;

    quant_x_kernel<<<M, 256, 0, stream>>>(x, xb, rs);
    quant_w_kernel<<<((size_t)N * K / 4) / 256, 256, 0, stream>>>(wq, wb);

    constexpr int NWG = (M / BM) * (N / BN);  // 1024
    gemm_i8_kernel<<<NWG, 512, 0, stream>>>(xb, wb, rs, scale, bias, out);
}